// Round 1
// baseline (144.569 us; speedup 1.0000x reference)
//
#include <hip/hip_runtime.h>

// R8: R7 structure (best: 54.2us/dispatch) with ROWS=2 -> ROWS=1.
// Theory: kernel is VALU-issue-bound (VALUBusy 66%, HBM 4%), with ~half the
// issue cycles in quarter-rate transcendentals (392 exp2 + 41 rcp per row).
// The 34% idle is latency under-coverage: grid at ROWS=2 is 1024 blocks ->
// 4096 waves -> 16 waves/CU = 50% occupancy HARD CAP (measured 30.8%), i.e.
// only 4 waves/SIMD to cover exp->sum->rcp chains. ROWS=1 doubles the grid
// (2048 blocks, 8192 waves, 100% cap); __launch_bounds__(256,8) tells the
// allocator to stay <=64 VGPR (R7 used 52 at ROWS=2; ROWS=1 needs less).
// Prior session tested ROWS=4 (regressed) but never ROWS=1.
// Kept identical: s_load weight path (no LDS, no barrier), exp2-domain
// softmax/sigmoid with per-row attained-max shift, Montgomery-batched
// sigmoid rcps, packed fp32 (v_pk_fma_f32), tree sums, x loads issued first.

typedef float v2f __attribute__((ext_vector_type(2)));

#define LOG2E 1.44269504088896340736f
#define ROWS 1

__device__ __forceinline__ float rcpf(float a) { return __builtin_amdgcn_rcpf(a); }

#if __has_builtin(__builtin_amdgcn_exp2f)
__device__ __forceinline__ float exp2_fast(float a) { return __builtin_amdgcn_exp2f(a); }
#else
__device__ __forceinline__ float exp2_fast(float a) { return __expf(0.6931471805599453f * a); }
#endif

__global__ __launch_bounds__(256, 8) void fused_attn_mlp(
    const float* __restrict__ x,
    const float* __restrict__ wq,
    const float* __restrict__ wk,
    const float* __restrict__ wv,
    const float* __restrict__ Wh,
    const float* __restrict__ bh,
    const float* __restrict__ Wo,
    const float* __restrict__ bo,
    float* __restrict__ out,
    int B)
{
    const int t = threadIdx.x;
    const int b0 = blockIdx.x * (256 * ROWS) + t;

    bool valid[ROWS];
    #pragma unroll
    for (int r = 0; r < ROWS; ++r) valid[r] = (b0 + r * 256) < B;

    // ---- issue x loads first (VMEM latency hides under s_load setup) ----
    float4 xraw[ROWS][4];
    #pragma unroll
    for (int r = 0; r < ROWS; ++r) {
        if (valid[r]) {
            const float4* xr = reinterpret_cast<const float4*>(x) + (size_t)(b0 + r * 256) * 4;
            xraw[r][0] = xr[0]; xraw[r][1] = xr[1]; xraw[r][2] = xr[2]; xraw[r][3] = xr[3];
        } else {
            xraw[r][0] = xraw[r][1] = xraw[r][2] = xraw[r][3] = float4{0.f,0.f,0.f,0.f};
        }
    }

    // ---- unpack x rows ----
    float xs[ROWS][16];
    v2f xv2[ROWS][8];
    #pragma unroll
    for (int r = 0; r < ROWS; ++r) {
        xs[r][0]=xraw[r][0].x; xs[r][1]=xraw[r][0].y; xs[r][2]=xraw[r][0].z; xs[r][3]=xraw[r][0].w;
        xs[r][4]=xraw[r][1].x; xs[r][5]=xraw[r][1].y; xs[r][6]=xraw[r][1].z; xs[r][7]=xraw[r][1].w;
        xs[r][8]=xraw[r][2].x; xs[r][9]=xraw[r][2].y; xs[r][10]=xraw[r][2].z; xs[r][11]=xraw[r][2].w;
        xs[r][12]=xraw[r][3].x; xs[r][13]=xraw[r][3].y; xs[r][14]=xraw[r][3].z; xs[r][15]=xraw[r][3].w;
        #pragma unroll
        for (int p = 0; p < 8; ++p) { v2f v; v[0]=xs[r][2*p]; v[1]=xs[r][2*p+1]; xv2[r][p]=v; }
    }

    // ---- attention block 1 (D=16), exp2 domain ----
    const float kq1 = wk[0] * wq[0] * LOG2E;
    const float v1  = wv[0];

    float xmx[ROWS], xmn[ROWS];
    #pragma unroll
    for (int r = 0; r < ROWS; ++r) {
        float mx = xs[r][0], mn = xs[r][0];
        #pragma unroll
        for (int i = 1; i < 16; ++i) { mx = fmaxf(mx, xs[r][i]); mn = fminf(mn, xs[r][i]); }
        xmx[r] = mx; xmn[r] = mn;
    }

    v2f o1v[ROWS][8];
    #pragma unroll
    for (int r = 0; r < ROWS; ++r)
        #pragma unroll
        for (int p = 0; p < 8; ++p) o1v[r][p] = (v2f)(0.f);

    #pragma unroll
    for (int i = 0; i < 16; ++i) {
        v2f e2[ROWS][8];
        float w[ROWS];
        #pragma unroll
        for (int r = 0; r < ROWS; ++r) {
            const float c = kq1 * xs[r][i];
            const float m = fmaxf(c * xmx[r], c * xmn[r]);   // exact attained max -> args <= 0
            v2f cc; cc[0]=c; cc[1]=c;
            v2f mm; mm[0]=m; mm[1]=m;
            #pragma unroll
            for (int p = 0; p < 8; ++p) {
                v2f a = cc * xv2[r][p] - mm;                 // v_pk_fma_f32
                v2f e; e[0] = exp2_fast(a[0]); e[1] = exp2_fast(a[1]);
                e2[r][p] = e;
            }
            v2f s01 = e2[r][0] + e2[r][1];
            v2f s23 = e2[r][2] + e2[r][3];
            v2f s45 = e2[r][4] + e2[r][5];
            v2f s67 = e2[r][6] + e2[r][7];
            v2f sv  = (s01 + s23) + (s45 + s67);
            w[r] = v1 * xs[r][i] * rcpf(sv[0] + sv[1]);
        }
        #pragma unroll
        for (int r = 0; r < ROWS; ++r) {
            v2f ww; ww[0]=w[r]; ww[1]=w[r];
            #pragma unroll
            for (int p = 0; p < 8; ++p) o1v[r][p] += ww * e2[r][p];
        }
    }

    // ---- fused MLP: 16 -> 64 sigmoid -> 8. Weights read at UNIFORM global
    //      indices -> s_load (scalar pipe). Sigmoid rcps Montgomery-batched. ----
    v2f x2v[ROWS][4];
    #pragma unroll
    for (int r = 0; r < ROWS; ++r)
        #pragma unroll
        for (int p = 0; p < 4; ++p) { v2f v; v[0]=bo[2*p]; v[1]=bo[2*p+1]; x2v[r][p]=v; }

    const v2f* Wh2 = reinterpret_cast<const v2f*>(Wh);   // [64][8] pairs
    const v2f* Wo2 = reinterpret_cast<const v2f*>(Wo);   // [8][32] pairs
    (void)Wo2;

    #pragma unroll 2
    for (int g = 0; g < 16; ++g) {
        float apre[ROWS][4];
        #pragma unroll
        for (int hh = 0; hh < 4; ++hh) {
            const int h = g * 4 + hh;
            v2f whr[8];
            #pragma unroll
            for (int p = 0; p < 8; ++p) whr[p] = Wh2[h * 8 + p];   // uniform -> s_load
            const float bhh = bh[h];
            #pragma unroll
            for (int r = 0; r < ROWS; ++r) {
                v2f acc = whr[0] * o1v[r][0];
                #pragma unroll
                for (int p = 1; p < 8; ++p) acc += whr[p] * o1v[r][p];
                apre[r][hh] = acc[0] + acc[1] + bhh;
            }
        }
        float sg[ROWS][4];
        #pragma unroll
        for (int r = 0; r < ROWS; ++r) {
            // clamp inert for a > -20.8 (sigma < 1e-9 there); keeps
            // d = 1+2^la <= 1+2^30, so prod4 <= 2^121 (no overflow).
            float d[4];
            #pragma unroll
            for (int hh = 0; hh < 4; ++hh) {
                const float la = fminf(-apre[r][hh] * LOG2E, 30.f);
                d[hh] = 1.f + exp2_fast(la);
            }
            const float p01  = d[0] * d[1];
            const float p012 = p01 * d[2];
            const float rq   = rcpf(p012 * d[3]);
            const float i3 = rq * p012;
            const float tq = rq * d[3];      // 1/(d0 d1 d2)
            const float i2 = tq * p01;
            const float t2 = tq * d[2];      // 1/(d0 d1)
            sg[r][0] = t2 * d[1];
            sg[r][1] = t2 * d[0];
            sg[r][2] = i2;
            sg[r][3] = i3;
        }
        // x2[o] += Wo[o][h] * sg[h] for the 4 h's of this group; Wo accessed
        // at uniform indices (o compile-time, h unrolled) -> s_load.
        #pragma unroll
        for (int hh = 0; hh < 4; ++hh) {
            const int h = g * 4 + hh;
            #pragma unroll
            for (int p = 0; p < 4; ++p) {      // p = output pair (o = 2p, 2p+1)
                v2f wo2;
                wo2[0] = Wo[(2 * p) * 64 + h];       // uniform scalar loads
                wo2[1] = Wo[(2 * p + 1) * 64 + h];
                #pragma unroll
                for (int r = 0; r < ROWS; ++r) {
                    v2f sgv; sgv[0] = sg[r][hh]; sgv[1] = sg[r][hh];
                    x2v[r][p] += wo2 * sgv;
                }
            }
        }
    }

    // ---- attention block 2 (D=8), exp2 domain; LOG2E folded into o2 ----
    const float kq2 = wk[1] * wq[1] * LOG2E;
    const float v2s = wv[1] * LOG2E;

    float ys[ROWS][8];
    float ymx[ROWS], ymn[ROWS];
    #pragma unroll
    for (int r = 0; r < ROWS; ++r) {
        #pragma unroll
        for (int i = 0; i < 8; ++i) ys[r][i] = x2v[r][i >> 1][i & 1];
        float mx = ys[r][0], mn = ys[r][0];
        #pragma unroll
        for (int i = 1; i < 8; ++i) { mx = fmaxf(mx, ys[r][i]); mn = fminf(mn, ys[r][i]); }
        ymx[r] = mx; ymn[r] = mn;
    }

    v2f o2v[ROWS][4];
    #pragma unroll
    for (int r = 0; r < ROWS; ++r)
        #pragma unroll
        for (int p = 0; p < 4; ++p) o2v[r][p] = (v2f)(0.f);

    #pragma unroll
    for (int i = 0; i < 8; ++i) {
        v2f e2[ROWS][4];
        float w[ROWS];
        #pragma unroll
        for (int r = 0; r < ROWS; ++r) {
            const float c = kq2 * ys[r][i];
            const float m = fmaxf(c * ymx[r], c * ymn[r]);
            v2f cc; cc[0]=c; cc[1]=c;
            v2f mm; mm[0]=m; mm[1]=m;
            #pragma unroll
            for (int p = 0; p < 4; ++p) {
                v2f a = cc * x2v[r][p] - mm;
                v2f e; e[0] = exp2_fast(a[0]); e[1] = exp2_fast(a[1]);
                e2[r][p] = e;
            }
            v2f sv = (e2[r][0] + e2[r][1]) + (e2[r][2] + e2[r][3]);
            w[r] = v2s * ys[r][i] * rcpf(sv[0] + sv[1]);
        }
        #pragma unroll
        for (int r = 0; r < ROWS; ++r) {
            v2f ww; ww[0]=w[r]; ww[1]=w[r];
            #pragma unroll
            for (int p = 0; p < 4; ++p) o2v[r][p] += ww * e2[r][p];
        }
    }

    // ---- final softmax (log2 domain) + dot with x[8:16] ----
    #pragma unroll
    for (int r = 0; r < ROWS; ++r) {
        float o2s[8];
        #pragma unroll
        for (int i = 0; i < 8; ++i) o2s[i] = o2v[r][i >> 1][i & 1];
        float m2 = o2s[0];
        #pragma unroll
        for (int i = 1; i < 8; ++i) m2 = fmaxf(m2, o2s[i]);
        v2f mm2; mm2[0]=m2; mm2[1]=m2;
        v2f se = (v2f)(0.f), de = (v2f)(0.f);
        #pragma unroll
        for (int p = 0; p < 4; ++p) {
            v2f a = o2v[r][p] - mm2;
            v2f e; e[0] = exp2_fast(a[0]); e[1] = exp2_fast(a[1]);
            se += e;
            v2f xp; xp[0]=xs[r][8+2*p]; xp[1]=xs[r][9+2*p];
            de += xp * e;
        }
        if (valid[r]) out[b0 + r * 256] = (de[0] + de[1]) * rcpf(se[0] + se[1]);
    }
}

extern "C" void kernel_launch(void* const* d_in, const int* in_sizes, int n_in,
                              void* d_out, int out_size, void* d_ws, size_t ws_size,
                              hipStream_t stream) {
    const float* x  = (const float*)d_in[0];
    const float* wq = (const float*)d_in[1];
    const float* wk = (const float*)d_in[2];
    const float* wv = (const float*)d_in[3];
    const float* Wh = (const float*)d_in[4];
    const float* bh = (const float*)d_in[5];
    const float* Wo = (const float*)d_in[6];
    const float* bo = (const float*)d_in[7];
    float* out = (float*)d_out;

    const int B = in_sizes[0] / 16;
    const int block = 256;
    const int rows_per_block = block * ROWS;
    const int grid = (B + rows_per_block - 1) / rows_per_block;
    fused_attn_mlp<<<grid, block, 0, stream>>>(x, wq, wk, wv, Wh, bh, Wo, bo, out, B);
}

// Round 2
// 124.267 us; speedup vs baseline: 1.1634x; 1.1634x over previous
//
#include <hip/hip_runtime.h>

// R9: ROWS=1 retry with spill-safe __launch_bounds__(256, 4).
// R8 post-mortem: (256,8) forced VGPR 52->32, below the ~50 live floats ->
// scratch spills (WRITE_SIZE 2MB -> 43MB, FETCH +6MB), dur 54.2 -> 68.7us.
// Occupancy DID rise 30->54 as predicted, so the occupancy theory is
// confounded, not falsified. This round: same ROWS=1 grid-doubling
// (2048 blocks = 8192 waves = 32/CU = 100% cap) but with the R7 bound
// (256,4) -> VGPR cap 128, no spill. Natural allocation at ROWS=1 should
// be ~40-52 (R7 used 52 for TWO rows); if <=64, HW grants 8 waves/SIMD.
// Decision rule: clean counters but dur >= 54us -> occupancy lever is dead,
// pivot to symmetric-attn1 exp reduction (256 -> 152 exps) next round.
// Kept identical: s_load weight path (no LDS, no barrier), exp2-domain
// softmax/sigmoid with per-row attained-max shift, Montgomery-batched
// sigmoid rcps, packed fp32 (v_pk_fma_f32), tree sums, x loads issued first.

typedef float v2f __attribute__((ext_vector_type(2)));

#define LOG2E 1.44269504088896340736f
#define ROWS 1

__device__ __forceinline__ float rcpf(float a) { return __builtin_amdgcn_rcpf(a); }

#if __has_builtin(__builtin_amdgcn_exp2f)
__device__ __forceinline__ float exp2_fast(float a) { return __builtin_amdgcn_exp2f(a); }
#else
__device__ __forceinline__ float exp2_fast(float a) { return __expf(0.6931471805599453f * a); }
#endif

__global__ __launch_bounds__(256, 4) void fused_attn_mlp(
    const float* __restrict__ x,
    const float* __restrict__ wq,
    const float* __restrict__ wk,
    const float* __restrict__ wv,
    const float* __restrict__ Wh,
    const float* __restrict__ bh,
    const float* __restrict__ Wo,
    const float* __restrict__ bo,
    float* __restrict__ out,
    int B)
{
    const int t = threadIdx.x;
    const int b0 = blockIdx.x * (256 * ROWS) + t;

    bool valid[ROWS];
    #pragma unroll
    for (int r = 0; r < ROWS; ++r) valid[r] = (b0 + r * 256) < B;

    // ---- issue x loads first (VMEM latency hides under s_load setup) ----
    float4 xraw[ROWS][4];
    #pragma unroll
    for (int r = 0; r < ROWS; ++r) {
        if (valid[r]) {
            const float4* xr = reinterpret_cast<const float4*>(x) + (size_t)(b0 + r * 256) * 4;
            xraw[r][0] = xr[0]; xraw[r][1] = xr[1]; xraw[r][2] = xr[2]; xraw[r][3] = xr[3];
        } else {
            xraw[r][0] = xraw[r][1] = xraw[r][2] = xraw[r][3] = float4{0.f,0.f,0.f,0.f};
        }
    }

    // ---- unpack x rows ----
    float xs[ROWS][16];
    v2f xv2[ROWS][8];
    #pragma unroll
    for (int r = 0; r < ROWS; ++r) {
        xs[r][0]=xraw[r][0].x; xs[r][1]=xraw[r][0].y; xs[r][2]=xraw[r][0].z; xs[r][3]=xraw[r][0].w;
        xs[r][4]=xraw[r][1].x; xs[r][5]=xraw[r][1].y; xs[r][6]=xraw[r][1].z; xs[r][7]=xraw[r][1].w;
        xs[r][8]=xraw[r][2].x; xs[r][9]=xraw[r][2].y; xs[r][10]=xraw[r][2].z; xs[r][11]=xraw[r][2].w;
        xs[r][12]=xraw[r][3].x; xs[r][13]=xraw[r][3].y; xs[r][14]=xraw[r][3].z; xs[r][15]=xraw[r][3].w;
        #pragma unroll
        for (int p = 0; p < 8; ++p) { v2f v; v[0]=xs[r][2*p]; v[1]=xs[r][2*p+1]; xv2[r][p]=v; }
    }

    // ---- attention block 1 (D=16), exp2 domain ----
    const float kq1 = wk[0] * wq[0] * LOG2E;
    const float v1  = wv[0];

    float xmx[ROWS], xmn[ROWS];
    #pragma unroll
    for (int r = 0; r < ROWS; ++r) {
        float mx = xs[r][0], mn = xs[r][0];
        #pragma unroll
        for (int i = 1; i < 16; ++i) { mx = fmaxf(mx, xs[r][i]); mn = fminf(mn, xs[r][i]); }
        xmx[r] = mx; xmn[r] = mn;
    }

    v2f o1v[ROWS][8];
    #pragma unroll
    for (int r = 0; r < ROWS; ++r)
        #pragma unroll
        for (int p = 0; p < 8; ++p) o1v[r][p] = (v2f)(0.f);

    #pragma unroll
    for (int i = 0; i < 16; ++i) {
        v2f e2[ROWS][8];
        float w[ROWS];
        #pragma unroll
        for (int r = 0; r < ROWS; ++r) {
            const float c = kq1 * xs[r][i];
            const float m = fmaxf(c * xmx[r], c * xmn[r]);   // exact attained max -> args <= 0
            v2f cc; cc[0]=c; cc[1]=c;
            v2f mm; mm[0]=m; mm[1]=m;
            #pragma unroll
            for (int p = 0; p < 8; ++p) {
                v2f a = cc * xv2[r][p] - mm;                 // v_pk_fma_f32
                v2f e; e[0] = exp2_fast(a[0]); e[1] = exp2_fast(a[1]);
                e2[r][p] = e;
            }
            v2f s01 = e2[r][0] + e2[r][1];
            v2f s23 = e2[r][2] + e2[r][3];
            v2f s45 = e2[r][4] + e2[r][5];
            v2f s67 = e2[r][6] + e2[r][7];
            v2f sv  = (s01 + s23) + (s45 + s67);
            w[r] = v1 * xs[r][i] * rcpf(sv[0] + sv[1]);
        }
        #pragma unroll
        for (int r = 0; r < ROWS; ++r) {
            v2f ww; ww[0]=w[r]; ww[1]=w[r];
            #pragma unroll
            for (int p = 0; p < 8; ++p) o1v[r][p] += ww * e2[r][p];
        }
    }

    // ---- fused MLP: 16 -> 64 sigmoid -> 8. Weights read at UNIFORM global
    //      indices -> s_load (scalar pipe). Sigmoid rcps Montgomery-batched. ----
    v2f x2v[ROWS][4];
    #pragma unroll
    for (int r = 0; r < ROWS; ++r)
        #pragma unroll
        for (int p = 0; p < 4; ++p) { v2f v; v[0]=bo[2*p]; v[1]=bo[2*p+1]; x2v[r][p]=v; }

    const v2f* Wh2 = reinterpret_cast<const v2f*>(Wh);   // [64][8] pairs

    #pragma unroll 2
    for (int g = 0; g < 16; ++g) {
        float apre[ROWS][4];
        #pragma unroll
        for (int hh = 0; hh < 4; ++hh) {
            const int h = g * 4 + hh;
            v2f whr[8];
            #pragma unroll
            for (int p = 0; p < 8; ++p) whr[p] = Wh2[h * 8 + p];   // uniform -> s_load
            const float bhh = bh[h];
            #pragma unroll
            for (int r = 0; r < ROWS; ++r) {
                v2f acc = whr[0] * o1v[r][0];
                #pragma unroll
                for (int p = 1; p < 8; ++p) acc += whr[p] * o1v[r][p];
                apre[r][hh] = acc[0] + acc[1] + bhh;
            }
        }
        float sg[ROWS][4];
        #pragma unroll
        for (int r = 0; r < ROWS; ++r) {
            // clamp inert for a > -20.8 (sigma < 1e-9 there); keeps
            // d = 1+2^la <= 1+2^30, so prod4 <= 2^121 (no overflow).
            float d[4];
            #pragma unroll
            for (int hh = 0; hh < 4; ++hh) {
                const float la = fminf(-apre[r][hh] * LOG2E, 30.f);
                d[hh] = 1.f + exp2_fast(la);
            }
            const float p01  = d[0] * d[1];
            const float p012 = p01 * d[2];
            const float rq   = rcpf(p012 * d[3]);
            const float i3 = rq * p012;
            const float tq = rq * d[3];      // 1/(d0 d1 d2)
            const float i2 = tq * p01;
            const float t2 = tq * d[2];      // 1/(d0 d1)
            sg[r][0] = t2 * d[1];
            sg[r][1] = t2 * d[0];
            sg[r][2] = i2;
            sg[r][3] = i3;
        }
        // x2[o] += Wo[o][h] * sg[h] for the 4 h's of this group; Wo accessed
        // at uniform indices (o compile-time, h unrolled) -> s_load.
        #pragma unroll
        for (int hh = 0; hh < 4; ++hh) {
            const int h = g * 4 + hh;
            #pragma unroll
            for (int p = 0; p < 4; ++p) {      // p = output pair (o = 2p, 2p+1)
                v2f wo2;
                wo2[0] = Wo[(2 * p) * 64 + h];       // uniform scalar loads
                wo2[1] = Wo[(2 * p + 1) * 64 + h];
                #pragma unroll
                for (int r = 0; r < ROWS; ++r) {
                    v2f sgv; sgv[0] = sg[r][hh]; sgv[1] = sg[r][hh];
                    x2v[r][p] += wo2 * sgv;
                }
            }
        }
    }

    // ---- attention block 2 (D=8), exp2 domain; LOG2E folded into o2 ----
    const float kq2 = wk[1] * wq[1] * LOG2E;
    const float v2s = wv[1] * LOG2E;

    float ys[ROWS][8];
    float ymx[ROWS], ymn[ROWS];
    #pragma unroll
    for (int r = 0; r < ROWS; ++r) {
        #pragma unroll
        for (int i = 0; i < 8; ++i) ys[r][i] = x2v[r][i >> 1][i & 1];
        float mx = ys[r][0], mn = ys[r][0];
        #pragma unroll
        for (int i = 1; i < 8; ++i) { mx = fmaxf(mx, ys[r][i]); mn = fminf(mn, ys[r][i]); }
        ymx[r] = mx; ymn[r] = mn;
    }

    v2f o2v[ROWS][4];
    #pragma unroll
    for (int r = 0; r < ROWS; ++r)
        #pragma unroll
        for (int p = 0; p < 4; ++p) o2v[r][p] = (v2f)(0.f);

    #pragma unroll
    for (int i = 0; i < 8; ++i) {
        v2f e2[ROWS][4];
        float w[ROWS];
        #pragma unroll
        for (int r = 0; r < ROWS; ++r) {
            const float c = kq2 * ys[r][i];
            const float m = fmaxf(c * ymx[r], c * ymn[r]);
            v2f cc; cc[0]=c; cc[1]=c;
            v2f mm; mm[0]=m; mm[1]=m;
            #pragma unroll
            for (int p = 0; p < 4; ++p) {
                v2f a = cc * x2v[r][p] - mm;
                v2f e; e[0] = exp2_fast(a[0]); e[1] = exp2_fast(a[1]);
                e2[r][p] = e;
            }
            v2f sv = (e2[r][0] + e2[r][1]) + (e2[r][2] + e2[r][3]);
            w[r] = v2s * ys[r][i] * rcpf(sv[0] + sv[1]);
        }
        #pragma unroll
        for (int r = 0; r < ROWS; ++r) {
            v2f ww; ww[0]=w[r]; ww[1]=w[r];
            #pragma unroll
            for (int p = 0; p < 4; ++p) o2v[r][p] += ww * e2[r][p];
        }
    }

    // ---- final softmax (log2 domain) + dot with x[8:16] ----
    #pragma unroll
    for (int r = 0; r < ROWS; ++r) {
        float o2s[8];
        #pragma unroll
        for (int i = 0; i < 8; ++i) o2s[i] = o2v[r][i >> 1][i & 1];
        float m2 = o2s[0];
        #pragma unroll
        for (int i = 1; i < 8; ++i) m2 = fmaxf(m2, o2s[i]);
        v2f mm2; mm2[0]=m2; mm2[1]=m2;
        v2f se = (v2f)(0.f), de = (v2f)(0.f);
        #pragma unroll
        for (int p = 0; p < 4; ++p) {
            v2f a = o2v[r][p] - mm2;
            v2f e; e[0] = exp2_fast(a[0]); e[1] = exp2_fast(a[1]);
            se += e;
            v2f xp; xp[0]=xs[r][8+2*p]; xp[1]=xs[r][9+2*p];
            de += xp * e;
        }
        if (valid[r]) out[b0 + r * 256] = (de[0] + de[1]) * rcpf(se[0] + se[1]);
    }
}

extern "C" void kernel_launch(void* const* d_in, const int* in_sizes, int n_in,
                              void* d_out, int out_size, void* d_ws, size_t ws_size,
                              hipStream_t stream) {
    const float* x  = (const float*)d_in[0];
    const float* wq = (const float*)d_in[1];
    const float* wk = (const float*)d_in[2];
    const float* wv = (const float*)d_in[3];
    const float* Wh = (const float*)d_in[4];
    const float* bh = (const float*)d_in[5];
    const float* Wo = (const float*)d_in[6];
    const float* bo = (const float*)d_in[7];
    float* out = (float*)d_out;

    const int B = in_sizes[0] / 16;
    const int block = 256;
    const int rows_per_block = block * ROWS;
    const int grid = (B + rows_per_block - 1) / rows_per_block;
    fused_attn_mlp<<<grid, block, 0, stream>>>(x, wq, wk, wv, Wh, bh, Wo, bo, out, B);
}